// Round 10
// baseline (2688.563 us; speedup 1.0000x reference)
//
#include <hip/hip_runtime.h>
#include <hip/hip_bf16.h>

// Problem constants (match reference setup_inputs)
#define Bb 64
#define Tt 256
#define Ee 300
#define Hh 512
#define NSTEP (2 * Tt - 1)  // 511
#define NNODE (Tt - 1)      // 255
#define N5H (5 * Hh)        // 2560

// Group decomposition: 4 independent groups x 64 blocks; each group owns 16
// batches end-to-end. Block = member 'mem' of group 'grp' owns 8 j-cols.
#define NG 4
#define GBATCH 16
#define JPB 8
#define NC 40     // JPB * 5 gate-cols per block
#define MBREC 32  // mailbox record: 4 self-tagged u64 words (tag<<32 | h1<<16 | h0)
#define CSTR 48   // csf row stride (>= 48: MFMA writes cols 0..47; 44 was the R8/R9 bug)

typedef __bf16 v8bf __attribute__((ext_vector_type(8)));
typedef float v4f __attribute__((ext_vector_type(4)));
typedef unsigned long long u64;
typedef unsigned int u32;
typedef unsigned char u8;

__device__ __forceinline__ float sigm(float x) { return 1.f / (1.f + __expf(-x)); }
__device__ __forceinline__ u64 ald64(const u64* p) {
    return __hip_atomic_load(p, __ATOMIC_RELAXED, __HIP_MEMORY_SCOPE_AGENT);
}
__device__ __forceinline__ u32 ald32(const u32* p) {
    return __hip_atomic_load(p, __ATOMIC_RELAXED, __HIP_MEMORY_SCOPE_AGENT);
}
__device__ __forceinline__ void ast32(u32* p, u32 v) {
    __hip_atomic_store(p, v, __ATOMIC_RELAXED, __HIP_MEMORY_SCOPE_AGENT);
}
__device__ __forceinline__ void ast64(u64* p, u64 v) {
    __hip_atomic_store(p, v, __ATOMIC_RELAXED, __HIP_MEMORY_SCOPE_AGENT);
}

// ---------------------------------------------------------------------------
// Phase 1: leaf buffer projections. 32 rows/block.
// ---------------------------------------------------------------------------
#define LROWS 32
__global__ __launch_bounds__(256) void leaf_kernel(
    const float* __restrict__ x, const float* __restrict__ Wx,
    const float* __restrict__ bx, const float* __restrict__ Wg,
    const float* __restrict__ bg,
    __hip_bfloat16* __restrict__ leaf_h, float* __restrict__ leaf_c)
{
    __shared__ __align__(16) float xs[LROWS][304];
    const int tid = threadIdx.x;
    const int n = blockIdx.x * 256 + tid;
    const long r0 = (long)blockIdx.y * LROWS;

    for (int i = tid; i < LROWS * Ee; i += 256) {
        int r = i / Ee, k = i - r * Ee;
        xs[r][k] = x[(r0 + r) * Ee + k];
    }
    __syncthreads();

    float accx[LROWS], accg[LROWS];
    const float bxv = bx[n], bgv = bg[n];
#pragma unroll
    for (int r = 0; r < LROWS; r++) { accx[r] = bxv; accg[r] = bgv; }

    for (int k = 0; k < Ee; k += 4) {
        float wx[4], wg[4];
#pragma unroll
        for (int u = 0; u < 4; u++) {
            wx[u] = Wx[(long)(k + u) * Hh + n];
            wg[u] = Wg[(long)(k + u) * Hh + n];
        }
#pragma unroll
        for (int r = 0; r < LROWS; r++) {
            const float4 xv = *(const float4*)&xs[r][k];
            accx[r] = fmaf(xv.x, wx[0], accx[r]);
            accx[r] = fmaf(xv.y, wx[1], accx[r]);
            accx[r] = fmaf(xv.z, wx[2], accx[r]);
            accx[r] = fmaf(xv.w, wx[3], accx[r]);
            accg[r] = fmaf(xv.x, wg[0], accg[r]);
            accg[r] = fmaf(xv.y, wg[1], accg[r]);
            accg[r] = fmaf(xv.z, wg[2], accg[r]);
            accg[r] = fmaf(xv.w, wg[3], accg[r]);
        }
    }
#pragma unroll
    for (int r = 0; r < LROWS; r++) {
        const float c = accx[r];
        const float h = sigm(accg[r]) * tanhf(c);
        const long idx = (r0 + r) * Hh + n;
        leaf_c[idx] = c;
        leaf_h[idx] = __float2bfloat16(h);
    }
}

// ---------------------------------------------------------------------------
// Phase 2: schedule. Per-group buckets (generic) + chain detection (fast):
// group is "fast" iff every batch is a pure chain (node nid has one child
// == node nid-1 and one leaf; level == nid+1; 255 nodes).
// fmeta[grp][lev][bloc] = coldleaf | hotside<<9 | root<<10 (lev>=2);
// fmeta[grp][1][bloc] = lleaf | rleaf<<9.
// ---------------------------------------------------------------------------
__global__ __launch_bounds__(64) void sched_kernel(
    const int* __restrict__ trans,
    int* __restrict__ node_l, int* __restrict__ node_r,
    int* __restrict__ root_src, int* __restrict__ offs,   // [NG*257]
    int* __restrict__ items, int* __restrict__ max_lv,    // [NG*GBATCH*NNODE], [NG]
    int* __restrict__ slots,                              // NG*256 bytes
    u32* __restrict__ fmeta, int* __restrict__ fastflag)  // [NG*256*16], [NG]
{
    __shared__ short stck[Bb][Tt];
    __shared__ unsigned char lvl[Bb][NNODE];
    __shared__ unsigned char trans_s[NSTEP][Bb];
    __shared__ int counts[NG][256];
    __shared__ int offs_s[NG][257];
    __shared__ int maxl_s[NG];
    __shared__ int fastsh[NG];
    const int b = threadIdx.x;

    if (b < NG) { maxl_s[b] = 0; fastsh[b] = 1; }
    for (int i = b; i < NG * 64; i += Bb) slots[i] = 0;
    for (int i = b; i < NG * 256; i += Bb) counts[i >> 8][i & 255] = 0;
    for (int i4 = b; i4 < (NSTEP * Bb) / 4; i4 += Bb) {
        const int4 v = ((const int4*)trans)[i4];
        const int f = 4 * i4;
        trans_s[(f + 0) >> 6][(f + 0) & 63] = (unsigned char)v.x;
        trans_s[(f + 1) >> 6][(f + 1) & 63] = (unsigned char)v.y;
        trans_s[(f + 2) >> 6][(f + 2) & 63] = (unsigned char)v.z;
        trans_s[(f + 3) >> 6][(f + 3) & 63] = (unsigned char)v.w;
    }
    __syncthreads();

    const int grp = b >> 4, bloc = b & 15;
    u32* fmG = fmeta + grp * 256 * GBATCH;

    int sp = 0, bp = Tt, nid = 0, maxl = 0, fast = 1;
    u32 meta1 = 0;
    for (int t = 0; t < NSTEP; t++) {
        if (trans_s[t][b] == 0) {
            bp -= 1;
            stck[b][sp] = (short)bp; sp += 1;
        } else {
            const int rs = stck[b][sp - 1];
            const int ls = stck[b][sp - 2];
            const int l_lv = (ls < Tt) ? 0 : (int)lvl[b][ls - Tt];
            const int r_lv = (rs < Tt) ? 0 : (int)lvl[b][rs - Tt];
            const int le = 1 + (l_lv > r_lv ? l_lv : r_lv);
            lvl[b][nid] = (unsigned char)le;
            node_l[b * NNODE + nid] = (l_lv << 9) | ls;
            node_r[b * NNODE + nid] = (r_lv << 9) | rs;
            if (le > maxl) maxl = le;
            if (nid == 0) {
                if (!(ls < Tt && rs < Tt)) fast = 0;
                meta1 = (u32)ls | ((u32)rs << 9);
            } else {
                const int lhot = (ls == Tt + nid - 1);
                const int rhot = (rs == Tt + nid - 1);
                const int cold = lhot ? rs : ls;
                if (!((lhot ^ rhot) && cold < Tt)) fast = 0;
                fmG[(nid + 1) * GBATCH + bloc] =
                    (u32)cold | ((u32)(rhot ? 1 : 0) << 9)
                    | ((nid == NNODE - 1) ? (1u << 10) : 0u);
            }
            if (le != nid + 1) fast = 0;
            sp -= 2;
            stck[b][sp] = (short)(Tt + nid); sp += 1;
            nid += 1;
        }
    }
    if (nid != NNODE || sp != 1 || stck[b][0] != Tt + NNODE - 1) fast = 0;
    fmG[1 * GBATCH + bloc] = meta1;
    root_src[b] = (int)stck[b][0];
    for (int i = 0; i < nid; i++) atomicAdd(&counts[grp][lvl[b][i]], 1);
    atomicMax(&maxl_s[grp], maxl);
    atomicAnd(&fastsh[grp], fast);
    __syncthreads();
    if (b < NG) {
        int acc = 0;
        for (int l = 0; l < 256; l++) { offs_s[b][l] = acc; acc += counts[b][l]; }
        offs_s[b][256] = acc;
        max_lv[b] = maxl_s[b];
        fastflag[b] = fastsh[b];
    }
    __syncthreads();
    for (int i = b; i < NG * 256; i += Bb) counts[i >> 8][i & 255] = offs_s[i >> 8][i & 255];
    __syncthreads();
    for (int i = 0; i < nid; i++) {
        const int pos = atomicAdd(&counts[grp][lvl[b][i]], 1);
        items[grp * (GBATCH * NNODE) + pos] = (b << 16) | i;
    }
    for (int i = b; i < NG * 257; i += Bb) offs[i] = offs_s[i / 257][i % 257];
}

// ---------------------------------------------------------------------------
// Phase 3: 4 groups x 64 blocks; block (grp, mem) holds 40 W_r cols in LDS.
// FAST path (chain trees): hot child h published via SELF-TAGGED 64-bit
// mailbox words (word = level<<32 | h1<<16 | h0; aligned 8B atomics are
// single-copy atomic, so tag+data are indivisible and no producer drain is
// needed). Hot child c stays in registers (self-produced); cold (leaf) A/c
// prefetched one level ahead; one __syncthreads per level.
// R10 FIX: csf row stride 44 -> 48. The MFMA stores cols 0..47 (3 tiles x
// 16); stride 44 made cols 44..47 (zero W-padding) overflow into the next
// row's gate cols 0..3 -> deterministic absmax 0.113 in R8/R9.
// GENERIC fallback = R7 path (slot barrier + node_h/node_c, proven).
// ---------------------------------------------------------------------------
__global__ __launch_bounds__(512) void tree_kernel(
    const float* __restrict__ Wr, const float* __restrict__ br,
    const __hip_bfloat16* __restrict__ leaf_h, const float* __restrict__ leaf_c,
    __hip_bfloat16* __restrict__ node_h, float* __restrict__ node_c,
    const int* __restrict__ node_l, const int* __restrict__ node_r,
    const int* __restrict__ root_src, const int* __restrict__ offs,
    const int* __restrict__ items, const int* __restrict__ max_lv,
    float* __restrict__ out, int* __restrict__ slots,
    const u32* __restrict__ fmeta, u8* __restrict__ mb,
    const int* __restrict__ fastflag)
{
    __shared__ __align__(16) __bf16 Wt[48][1032];  // [local col][k], pad +8
    __shared__ __align__(16) char pool[49408];     // fast csf (2*8*16*48*4=49152) / generic structs
    __shared__ float brs[48];

    const int tid = threadIdx.x;
    const int blk = blockIdx.x;
    const int grp = blk & 3;
    const int mem = blk >> 2;  // 0..63
    const int j0 = mem * JPB;

    // Load W_r slice bf16 transposed: local col c -> (gate=c%5, jl=c/5).
    for (int idx = tid; idx < 48 * 1024; idx += 512) {
        const int c = idx >> 10;
        const int k = idx & 1023;
        float v = 0.f;
        if (c < NC) v = Wr[(long)k * N5H + (c % 5) * Hh + j0 + c / 5];
        Wt[c][k] = (__bf16)v;
    }
    if (tid < 48) {
        float v = 0.f;
        if (tid < NC) v = br[(tid % 5) * Hh + j0 + tid / 5];
        brs[tid] = v;
    }
    __syncthreads();

    const int ML = max_lv[grp];
    const int wave = tid >> 6;
    const int lane = tid & 63;
    const int quad = lane >> 4;
    const int l15 = lane & 15;
    const int kq = wave;           // K slice [kq*128, +128); kq<4 left child
    const bool rightW = kq >= 4;

    if (fastflag[grp]) {
        // =================== FAST (chain) PATH ===================
        float* csf = (float*)pool;  // [2][8][16][CSTR]
        const int em = lane >> 2, ejj = (lane & 3) * 2;
        const u32* metaG = fmeta + grp * 256 * GBATCH;

        float bias[10];
        if (wave == 0) {
#pragma unroll
            for (int i = 0; i < 10; i++) bias[i] = brs[ejj * 5 + i];
        }
        float cv0 = 0.f, cv1 = 0.f;            // hot child c (self, registers)
        float ccold0 = 0.f, ccold1 = 0.f;      // cold (leaf) c for current lev
        float cnx0 = 0.f, cnx1 = 0.f;          // prefetched for lev+1
        float cl10 = 0.f, cl11 = 0.f, cr10 = 0.f, cr11 = 0.f;  // lev1 both-leaf c

        u32 meta_c = metaG[1 * GBATCH + l15];
        u32 meta_n = metaG[2 * GBATCH + l15];
        u32 metaE_c = 0, metaE_n = 0;
        if (wave == 0) {
            metaE_c = metaG[1 * GBATCH + em];
            metaE_n = metaG[2 * GBATCH + em];
            const int llf = metaE_c & 511, rlf = (metaE_c >> 9) & 511;
            const float* clp = leaf_c + ((long)(grp * GBATCH + em) * Tt + llf) * Hh + j0 + ejj;
            const float* crp = leaf_c + ((long)(grp * GBATCH + em) * Tt + rlf) * Hh + j0 + ejj;
            cl10 = clp[0]; cl11 = clp[1]; cr10 = crp[0]; cr11 = crp[1];
        }
        // lev1 A prefetch (both children leaves)
        v8bf a0, a1, a2, a3;
        {
            const int lf = rightW ? ((meta_c >> 9) & 511) : (meta_c & 511);
            const __hip_bfloat16* hp =
                leaf_h + ((long)(grp * GBATCH + l15) * Tt + lf) * Hh + (kq & 3) * 128 + quad * 8;
            a0 = *(const v8bf*)hp;        a1 = *(const v8bf*)(hp + 32);
            a2 = *(const v8bf*)(hp + 64); a3 = *(const v8bf*)(hp + 96);
        }

        for (int lev = 1; lev <= ML; lev++) {
            const int par = lev & 1;

            // ---- Phase 1: hot poll (self-tagged mailbox words) + MFMA ----
            bool hotlane = false;
            if (lev >= 2) hotlane = (((meta_c >> 9) & 1) == (rightW ? 1 : 0));
            if (__any(hotlane)) {
                const int par2 = (lev - 1) & 1;
                const u8* rb = mb + (size_t)(((grp * 2 + par2) * GBATCH + l15) * 64) * MBREC;
                const u32 tgt = (u32)(lev - 1);
                u32 dat[16];
                for (;;) {
                    bool ok = true;
                    if (hotlane) {
#pragma unroll
                        for (int t = 0; t < 4; t++) {
                            const u64* rp =
                                (const u64*)(rb + ((kq & 3) * 16 + t * 4 + quad) * MBREC);
#pragma unroll
                            for (int w = 0; w < 4; w++) {
                                const u64 v = ald64(rp + w);
                                dat[t * 4 + w] = (u32)v;
                                ok &= ((u32)(v >> 32) == tgt);
                            }
                        }
                    }
                    if (__all(ok)) break;
                }
                if (hotlane) {
                    union { u32 d[4]; v8bf v; } uv;
                    uv.d[0] = dat[0];  uv.d[1] = dat[1];  uv.d[2] = dat[2];  uv.d[3] = dat[3];  a0 = uv.v;
                    uv.d[0] = dat[4];  uv.d[1] = dat[5];  uv.d[2] = dat[6];  uv.d[3] = dat[7];  a1 = uv.v;
                    uv.d[0] = dat[8];  uv.d[1] = dat[9];  uv.d[2] = dat[10]; uv.d[3] = dat[11]; a2 = uv.v;
                    uv.d[0] = dat[12]; uv.d[1] = dat[13]; uv.d[2] = dat[14]; uv.d[3] = dat[15]; a3 = uv.v;
                }
            }
            {
                v8bf av[4] = {a0, a1, a2, a3};
#pragma unroll
                for (int nt = 0; nt < 3; nt++) {
                    v4f acc = {0.f, 0.f, 0.f, 0.f};
#pragma unroll
                    for (int t = 0; t < 4; t++) {
                        const v8bf wv = *(const v8bf*)&Wt[nt * 16 + l15][kq * 128 + t * 32 + quad * 8];
                        acc = __builtin_amdgcn_mfma_f32_16x16x32_bf16(av[t], wv, acc, 0, 0, 0);
                    }
#pragma unroll
                    for (int rg = 0; rg < 4; rg++)
                        csf[(((par * 8) + kq) * 16 + quad * 4 + rg) * CSTR + nt * 16 + l15] = acc[rg];
                }
            }

            // ---- Prefetch for lev+1 (cold A / cold c / meta) ----
            u32 meta_nn = 0, metaE_nn = 0;
            if (lev < ML) {
                const int l2 = (lev + 2 <= ML) ? (lev + 2) : ML;
                meta_nn = metaG[l2 * GBATCH + l15];
                const bool nhot = (((meta_n >> 9) & 1) == (rightW ? 1 : 0));
                if (!nhot) {
                    const int lf = meta_n & 511;
                    const __hip_bfloat16* hp =
                        leaf_h + ((long)(grp * GBATCH + l15) * Tt + lf) * Hh + (kq & 3) * 128 + quad * 8;
                    a0 = *(const v8bf*)hp;        a1 = *(const v8bf*)(hp + 32);
                    a2 = *(const v8bf*)(hp + 64); a3 = *(const v8bf*)(hp + 96);
                }
                if (wave == 0) {
                    metaE_nn = metaG[l2 * GBATCH + em];
                    const int lfE = metaE_n & 511;
                    const float* cp =
                        leaf_c + ((long)(grp * GBATCH + em) * Tt + lfE) * Hh + j0 + ejj;
                    cnx0 = cp[0]; cnx1 = cp[1];
                }
            }
            __syncthreads();

            // ---- Phase 2 (wave 0 tail): reduce + cell + self-tagged publish ----
            if (wave == 0) {
                float g10[10];
#pragma unroll
                for (int gi = 0; gi < 10; gi++) {
                    float s = bias[gi];
#pragma unroll
                    for (int w = 0; w < 8; w++)
                        s += csf[(((par * 8) + w) * 16 + em) * CSTR + ejj * 5 + gi];
                    g10[gi] = s;
                }
                float cl0, cl1, cr0, cr1;
                if (lev == 1) { cl0 = cl10; cl1 = cl11; cr0 = cr10; cr1 = cr11; }
                else if (((metaE_c >> 9) & 1) == 0) {  // left hot
                    cl0 = cv0; cl1 = cv1; cr0 = ccold0; cr1 = ccold1;
                } else {
                    cl0 = ccold0; cl1 = ccold1; cr0 = cv0; cr1 = cv1;
                }
                const float c0 = sigm(g10[0]) * tanhf(g10[3]) + sigm(g10[1]) * cl0 + sigm(g10[2]) * cr0;
                const float h0v = sigm(g10[4]) * tanhf(c0);
                const float c1 = sigm(g10[5]) * tanhf(g10[8]) + sigm(g10[6]) * cl1 + sigm(g10[7]) * cr1;
                const float h1v = sigm(g10[9]) * tanhf(c1);
                cv0 = c0; cv1 = c1;
                if (lev < ML) {
                    u8* rec = mb + (size_t)((((grp * 2 + par) * GBATCH + em) * 64 + mem)) * MBREC;
                    const __hip_bfloat16 hb0 = __float2bfloat16(h0v);
                    const __hip_bfloat16 hb1 = __float2bfloat16(h1v);
                    const u32 hp2 = (u32)(*(const unsigned short*)&hb0)
                                  | ((u32)(*(const unsigned short*)&hb1) << 16);
                    // self-tagged word: (level<<32)|data — atomic 8B, no drain needed
                    ast64((u64*)(rec + ejj * 4), ((u64)(u32)lev << 32) | (u64)hp2);
                }
                if (metaE_c & (1u << 10)) {
                    out[(long)(grp * GBATCH + em) * Hh + j0 + ejj] = h0v;
                    out[(long)(grp * GBATCH + em) * Hh + j0 + ejj + 1] = h1v;
                }
            }
            // rotate prefetched state
            meta_c = meta_n; meta_n = meta_nn;
            if (wave == 0) {
                metaE_c = metaE_n; metaE_n = metaE_nn;
                ccold0 = cnx0; ccold1 = cnx1;
            }
        }
        return;
    }

    // =================== GENERIC PATH (R7, proven) ===================
    float (*CsG)[16][52] = (float (*)[16][52])pool;              // [8][16][52]
    float (*CredG)[44] = (float (*)[44])(pool + 26624);          // [16][44]
    u64* hPlG = (u64*)(pool + 29440);
    u64* hPrG = (u64*)(pool + 29568);
    u64* cPlG = (u64*)(pool + 29696);
    u64* cPrG = (u64*)(pool + 29824);
    int* outmG = (int*)(pool + 29952);

    const int* offsG = offs + grp * 257;
    const int* itemsG = items + grp * (GBATCH * NNODE);
    u8* slotG = (u8*)slots + grp * 256;
    u32* node_h32 = (u32*)node_h;

    auto prep = [&](int base, int M, int plv) {
        if (lane < 16) {
            const int m = lane;
            const int it = itemsG[base + (m < M ? m : 0)];
            const int b = it >> 16;
            const int nd = it & 0xffff;
            const int lraw = node_l[b * NNODE + nd];
            const int rraw = node_r[b * NNODE + nd];
            const int ls = lraw & 511, llv = lraw >> 9;
            const int rs = rraw & 511, rlv = rraw >> 9;
            hPlG[m] = (ls < Tt) ? (u64)(leaf_h + ((long)b * Tt + ls) * Hh)
                                : (u64)(node_h + ((long)b * NNODE + (ls - Tt)) * Hh);
            cPlG[m] = (ls < Tt) ? (u64)(leaf_c + ((long)b * Tt + ls) * Hh)
                                : (u64)(node_c + ((long)b * NNODE + (ls - Tt)) * Hh);
            hPrG[m] = (rs < Tt) ? (u64)(leaf_h + ((long)b * Tt + rs) * Hh)
                                : (u64)(node_h + ((long)b * NNODE + (rs - Tt)) * Hh);
            cPrG[m] = (rs < Tt) ? (u64)(leaf_c + ((long)b * Tt + rs) * Hh)
                                : (u64)(node_c + ((long)b * NNODE + (rs - Tt)) * Hh);
            int fl = it;
            if (llv > 0 && llv == plv - 1) fl |= (1 << 27);
            if (rlv > 0 && rlv == plv - 1) fl |= (1 << 28);
            if (Tt + nd == root_src[b]) fl |= (1 << 30);
            if (m >= M) fl |= (1 << 29);
            outmG[m] = fl;
        }
    };

    auto epilogue = [&](float clv0, float clv1, float crv0, float crv1) {
        const int m = lane >> 2;
        const int jl2 = (lane & 3) * 2;
        const int info = outmG[m];
        if (!(info & (1 << 29))) {
            const int b = (info >> 16) & 63;
            const int nd = info & 0xffff;
            float cv[2], hv[2];
            const float clv[2] = {clv0, clv1};
            const float crv[2] = {crv0, crv1};
#pragma unroll
            for (int jj = 0; jj < 2; jj++) {
                const int jc = (jl2 + jj) * 5;
                const float iv = CredG[m][jc + 0];
                const float fl = CredG[m][jc + 1];
                const float fr = CredG[m][jc + 2];
                const float gv = CredG[m][jc + 3];
                const float ov = CredG[m][jc + 4];
                cv[jj] = sigm(iv) * tanhf(gv) + sigm(fl) * clv[jj] + sigm(fr) * crv[jj];
                hv[jj] = sigm(ov) * tanhf(cv[jj]);
            }
            union { float f[2]; u64 u; } cp;
            cp.f[0] = cv[0]; cp.f[1] = cv[1];
            ast64((u64*)(node_c + ((long)b * NNODE + nd) * Hh + j0 + jl2), cp.u);
            const __hip_bfloat16 h0 = __float2bfloat16(hv[0]);
            const __hip_bfloat16 h1 = __float2bfloat16(hv[1]);
            const u32 hpack = (u32)(*(const unsigned short*)&h0)
                            | ((u32)(*(const unsigned short*)&h1) << 16);
            ast32(node_h32 + ((long)b * NNODE + nd) * (Hh / 2) + (j0 + jl2) / 2, hpack);
            if (info & (1 << 30)) {
                out[(long)b * Hh + j0 + jl2] = hv[0];
                out[(long)b * Hh + j0 + jl2 + 1] = hv[1];
            }
        }
    };

    auto do_mfma = [&](v8bf a0, v8bf a1, v8bf a2, v8bf a3) {
        v8bf a[4] = {a0, a1, a2, a3};
#pragma unroll
        for (int nt = 0; nt < 3; nt++) {
            v4f acc = {0.f, 0.f, 0.f, 0.f};
#pragma unroll
            for (int t = 0; t < 4; t++) {
                const v8bf wv = *(const v8bf*)&Wt[nt * 16 + l15][kq * 128 + t * 32 + quad * 8];
                acc = __builtin_amdgcn_mfma_f32_16x16x32_bf16(a[t], wv, acc, 0, 0, 0);
            }
#pragma unroll
            for (int rg = 0; rg < 4; rg++)
                CsG[kq][quad * 4 + rg][nt * 16 + l15] = acc[rg];
        }
    };

    auto reduce = [&]() {
        for (int t = tid; t < 16 * NC; t += 512) {
            const int m = t / NC, c = t - m * NC;
            float r = brs[c];
#pragma unroll
            for (int w = 0; w < 8; w++) r += CsG[w][m][c];
            CredG[m][c] = r;
        }
    };

    if (wave == 0 && ML >= 1) {
        const int s1 = offsG[1], e1 = offsG[2];
        prep(s1, (e1 - s1 < 16) ? (e1 - s1) : 16, 1);
    }
    __syncthreads();

    for (int lev = 1; lev <= ML; lev++) {
        const int s = offsG[lev], e = offsG[lev + 1];

        const int infoA = outmG[l15];
        const bool hot = (infoA >> (27 + (kq >> 2))) & 1;
        const __hip_bfloat16* hp =
            (const __hip_bfloat16*)((kq < 4) ? hPlG[l15] : hPrG[l15]);
        const int kb = (kq & 3) * 128 + quad * 8;
        v8bf a0, a1, a2, a3;
        if (!hot) {
            a0 = *(const v8bf*)(hp + kb);
            a1 = *(const v8bf*)(hp + kb + 32);
            a2 = *(const v8bf*)(hp + kb + 64);
            a3 = *(const v8bf*)(hp + kb + 96);
        }
        float clv0 = 0.f, clv1 = 0.f, crv0 = 0.f, crv1 = 0.f;
        bool hotL = false, hotR = false;
        if (wave == 0) {
            const int ie = outmG[lane >> 2];
            hotL = (ie >> 27) & 1;
            hotR = (ie >> 28) & 1;
            const int jo = j0 + (lane & 3) * 2;
            if (!hotL) {
                union { u64 u; float f[2]; } t;
                t.u = *(const u64*)((const float*)cPlG[lane >> 2] + jo);
                clv0 = t.f[0]; clv1 = t.f[1];
            }
            if (!hotR) {
                union { u64 u; float f[2]; } t;
                t.u = *(const u64*)((const float*)cPrG[lane >> 2] + jo);
                crv0 = t.f[0]; crv1 = t.f[1];
            }
        }

        if (lev > 1 && wave == 0) {
            const u32 need = (u32)(lev - 1);
            const u32* sl = (const u32*)slotG + (lane & 15);
            for (;;) {
                const u32 v = ald32(sl);
                const bool ok = ((v & 0xffu) >= need) & (((v >> 8) & 0xffu) >= need)
                              & (((v >> 16) & 0xffu) >= need) & ((v >> 24) >= need);
                if (__all(ok)) break;
            }
        }
        __syncthreads();

        if (hot) {
            a0 = *(const v8bf*)(hp + kb);
            a1 = *(const v8bf*)(hp + kb + 32);
            a2 = *(const v8bf*)(hp + kb + 64);
            a3 = *(const v8bf*)(hp + kb + 96);
        }
        if (wave == 0) {
            const int jo = j0 + (lane & 3) * 2;
            if (hotL) {
                union { u64 u; float f[2]; } t;
                t.u = *(const u64*)((const float*)cPlG[lane >> 2] + jo);
                clv0 = t.f[0]; clv1 = t.f[1];
            }
            if (hotR) {
                union { u64 u; float f[2]; } t;
                t.u = *(const u64*)((const float*)cPrG[lane >> 2] + jo);
                crv0 = t.f[0]; crv1 = t.f[1];
            }
        }
        do_mfma(a0, a1, a2, a3);
        __syncthreads();
        reduce();
        __syncthreads();
        if (wave == 0) epilogue(clv0, clv1, crv0, crv1);

        for (int base = s + 16; base < e; base += 16) {
            __syncthreads();
            if (wave == 0) prep(base, (e - base < 16) ? (e - base) : 16, lev);
            __syncthreads();
            const __hip_bfloat16* hp2 =
                (const __hip_bfloat16*)((kq < 4) ? hPlG[l15] : hPrG[l15]);
            float xl0 = 0.f, xl1 = 0.f, xr0 = 0.f, xr1 = 0.f;
            if (wave == 0) {
                const int jo = j0 + (lane & 3) * 2;
                union { u64 u; float f[2]; } t;
                t.u = *(const u64*)((const float*)cPlG[lane >> 2] + jo);
                xl0 = t.f[0]; xl1 = t.f[1];
                t.u = *(const u64*)((const float*)cPrG[lane >> 2] + jo);
                xr0 = t.f[0]; xr1 = t.f[1];
            }
            do_mfma(*(const v8bf*)(hp2 + kb), *(const v8bf*)(hp2 + kb + 32),
                    *(const v8bf*)(hp2 + kb + 64), *(const v8bf*)(hp2 + kb + 96));
            __syncthreads();
            reduce();
            __syncthreads();
            if (wave == 0) epilogue(xl0, xl1, xr0, xr1);
        }

        // arrival: drain wave-0 sc1 stores, then byte slot store + next prep
        if (wave == 0) {
            __builtin_amdgcn_s_waitcnt(0);
            if (lev < ML) {
                if (lane == 0)
                    __hip_atomic_store(slotG + mem, (u8)lev,
                                       __ATOMIC_RELAXED, __HIP_MEMORY_SCOPE_AGENT);
                const int ns = offsG[lev + 1], ne = offsG[lev + 2];
                prep(ns, (ne - ns < 16) ? (ne - ns) : 16, lev + 1);
            }
        }
        __syncthreads();
    }
}

// ---------------------------------------------------------------------------
extern "C" void kernel_launch(void* const* d_in, const int* in_sizes, int n_in,
                              void* d_out, int out_size, void* d_ws, size_t ws_size,
                              hipStream_t stream)
{
    const float* x   = (const float*)d_in[0];
    const int* trans = (const int*)d_in[1];
    const float* Wx  = (const float*)d_in[2];
    const float* bx  = (const float*)d_in[3];
    const float* Wg  = (const float*)d_in[4];
    const float* bg  = (const float*)d_in[5];
    const float* Wr  = (const float*)d_in[6];
    const float* br  = (const float*)d_in[7];
    float* out = (float*)d_out;

    char* p = (char*)d_ws;
    auto take = [&](size_t bytes) -> char* {
        char* r = p;
        p += (bytes + 255) & ~(size_t)255;
        return r;
    };
    __hip_bfloat16* leaf_h = (__hip_bfloat16*)take((size_t)Bb * Tt * Hh * 2);
    float* leaf_c          = (float*)take((size_t)Bb * Tt * Hh * 4);
    __hip_bfloat16* node_h = (__hip_bfloat16*)take((size_t)Bb * NNODE * Hh * 2);
    float* node_c          = (float*)take((size_t)Bb * NNODE * Hh * 4);
    int* node_l   = (int*)take((size_t)Bb * NNODE * 4);
    int* node_r   = (int*)take((size_t)Bb * NNODE * 4);
    int* root_src = (int*)take(Bb * 4);
    int* offs     = (int*)take((size_t)NG * 257 * 4);
    int* items    = (int*)take((size_t)NG * GBATCH * NNODE * 4);
    int* max_lv   = (int*)take(NG * 4);
    int* slots    = (int*)take(NG * 256);
    u32* fmeta    = (u32*)take((size_t)NG * 256 * GBATCH * 4);        // 64 KB
    u8* mbox      = (u8*)take((size_t)NG * 2 * GBATCH * 64 * MBREC);  // 256 KB
    int* fastflag = (int*)take(NG * 4);

    hipLaunchKernelGGL(leaf_kernel, dim3(Hh / 256, (Bb * Tt) / LROWS), dim3(256), 0, stream,
                       x, Wx, bx, Wg, bg, leaf_h, leaf_c);
    hipLaunchKernelGGL(sched_kernel, dim3(1), dim3(64), 0, stream,
                       trans, node_l, node_r, root_src, offs, items, max_lv, slots,
                       fmeta, fastflag);

    void* args[] = { (void*)&Wr, (void*)&br, (void*)&leaf_h, (void*)&leaf_c,
                     (void*)&node_h, (void*)&node_c, (void*)&node_l, (void*)&node_r,
                     (void*)&root_src, (void*)&offs, (void*)&items, (void*)&max_lv,
                     (void*)&out, (void*)&slots, (void*)&fmeta, (void*)&mbox,
                     (void*)&fastflag };
    hipLaunchCooperativeKernel((const void*)tree_kernel, dim3(256), dim3(512),
                               args, 0, stream);
}

// Round 11
// 1694.840 us; speedup vs baseline: 1.5863x; 1.5863x over previous
//
#include <hip/hip_runtime.h>
#include <hip/hip_bf16.h>

// Problem constants (match reference setup_inputs)
#define Bb 64
#define Tt 256
#define Ee 300
#define Hh 512
#define NSTEP (2 * Tt - 1)  // 511
#define NNODE (Tt - 1)      // 255
#define N5H (5 * Hh)        // 2560

// Group decomposition: 4 independent groups x 64 blocks; each group owns 16
// batches end-to-end. Block = member 'mem' of group 'grp' owns 8 j-cols.
#define NG 4
#define GBATCH 16
#define JPB 8
#define NC 40     // JPB * 5 gate-cols per block
#define MBREC 32  // (legacy, unused by fast path)
#define CSTR 48   // csf row stride (MFMA writes cols 0..47; 44 was the R8/R9 bug)

typedef __bf16 v8bf __attribute__((ext_vector_type(8)));
typedef float v4f __attribute__((ext_vector_type(4)));
typedef unsigned long long u64;
typedef unsigned int u32;
typedef unsigned char u8;

__device__ __forceinline__ float sigm(float x) { return 1.f / (1.f + __expf(-x)); }
__device__ __forceinline__ u64 ald64(const u64* p) {
    return __hip_atomic_load(p, __ATOMIC_RELAXED, __HIP_MEMORY_SCOPE_AGENT);
}
__device__ __forceinline__ u32 ald32(const u32* p) {
    return __hip_atomic_load(p, __ATOMIC_RELAXED, __HIP_MEMORY_SCOPE_AGENT);
}
__device__ __forceinline__ void ast32(u32* p, u32 v) {
    __hip_atomic_store(p, v, __ATOMIC_RELAXED, __HIP_MEMORY_SCOPE_AGENT);
}
__device__ __forceinline__ void ast64(u64* p, u64 v) {
    __hip_atomic_store(p, v, __ATOMIC_RELAXED, __HIP_MEMORY_SCOPE_AGENT);
}

// ---------------------------------------------------------------------------
// Phase 1: leaf buffer projections. 32 rows/block.
// ---------------------------------------------------------------------------
#define LROWS 32
__global__ __launch_bounds__(256) void leaf_kernel(
    const float* __restrict__ x, const float* __restrict__ Wx,
    const float* __restrict__ bx, const float* __restrict__ Wg,
    const float* __restrict__ bg,
    __hip_bfloat16* __restrict__ leaf_h, float* __restrict__ leaf_c)
{
    __shared__ __align__(16) float xs[LROWS][304];
    const int tid = threadIdx.x;
    const int n = blockIdx.x * 256 + tid;
    const long r0 = (long)blockIdx.y * LROWS;

    for (int i = tid; i < LROWS * Ee; i += 256) {
        int r = i / Ee, k = i - r * Ee;
        xs[r][k] = x[(r0 + r) * Ee + k];
    }
    __syncthreads();

    float accx[LROWS], accg[LROWS];
    const float bxv = bx[n], bgv = bg[n];
#pragma unroll
    for (int r = 0; r < LROWS; r++) { accx[r] = bxv; accg[r] = bgv; }

    for (int k = 0; k < Ee; k += 4) {
        float wx[4], wg[4];
#pragma unroll
        for (int u = 0; u < 4; u++) {
            wx[u] = Wx[(long)(k + u) * Hh + n];
            wg[u] = Wg[(long)(k + u) * Hh + n];
        }
#pragma unroll
        for (int r = 0; r < LROWS; r++) {
            const float4 xv = *(const float4*)&xs[r][k];
            accx[r] = fmaf(xv.x, wx[0], accx[r]);
            accx[r] = fmaf(xv.y, wx[1], accx[r]);
            accx[r] = fmaf(xv.z, wx[2], accx[r]);
            accx[r] = fmaf(xv.w, wx[3], accx[r]);
            accg[r] = fmaf(xv.x, wg[0], accg[r]);
            accg[r] = fmaf(xv.y, wg[1], accg[r]);
            accg[r] = fmaf(xv.z, wg[2], accg[r]);
            accg[r] = fmaf(xv.w, wg[3], accg[r]);
        }
    }
#pragma unroll
    for (int r = 0; r < LROWS; r++) {
        const float c = accx[r];
        const float h = sigm(accg[r]) * tanhf(c);
        const long idx = (r0 + r) * Hh + n;
        leaf_c[idx] = c;
        leaf_h[idx] = __float2bfloat16(h);
    }
}

// ---------------------------------------------------------------------------
// Phase 2: schedule (unchanged from R10). Per-group buckets + chain detect.
// fmeta[grp][lev][bloc] = coldleaf | hotside<<9 | root<<10 (lev>=2);
// fmeta[grp][1][bloc] = lleaf | rleaf<<9.
// ---------------------------------------------------------------------------
__global__ __launch_bounds__(64) void sched_kernel(
    const int* __restrict__ trans,
    int* __restrict__ node_l, int* __restrict__ node_r,
    int* __restrict__ root_src, int* __restrict__ offs,   // [NG*257]
    int* __restrict__ items, int* __restrict__ max_lv,    // [NG*GBATCH*NNODE], [NG]
    int* __restrict__ slots,                              // NG*256 bytes
    u32* __restrict__ fmeta, int* __restrict__ fastflag)  // [NG*256*16], [NG]
{
    __shared__ short stck[Bb][Tt];
    __shared__ unsigned char lvl[Bb][NNODE];
    __shared__ unsigned char trans_s[NSTEP][Bb];
    __shared__ int counts[NG][256];
    __shared__ int offs_s[NG][257];
    __shared__ int maxl_s[NG];
    __shared__ int fastsh[NG];
    const int b = threadIdx.x;

    if (b < NG) { maxl_s[b] = 0; fastsh[b] = 1; }
    for (int i = b; i < NG * 64; i += Bb) slots[i] = 0;
    for (int i = b; i < NG * 256; i += Bb) counts[i >> 8][i & 255] = 0;
    for (int i4 = b; i4 < (NSTEP * Bb) / 4; i4 += Bb) {
        const int4 v = ((const int4*)trans)[i4];
        const int f = 4 * i4;
        trans_s[(f + 0) >> 6][(f + 0) & 63] = (unsigned char)v.x;
        trans_s[(f + 1) >> 6][(f + 1) & 63] = (unsigned char)v.y;
        trans_s[(f + 2) >> 6][(f + 2) & 63] = (unsigned char)v.z;
        trans_s[(f + 3) >> 6][(f + 3) & 63] = (unsigned char)v.w;
    }
    __syncthreads();

    const int grp = b >> 4, bloc = b & 15;
    u32* fmG = fmeta + grp * 256 * GBATCH;

    int sp = 0, bp = Tt, nid = 0, maxl = 0, fast = 1;
    u32 meta1 = 0;
    for (int t = 0; t < NSTEP; t++) {
        if (trans_s[t][b] == 0) {
            bp -= 1;
            stck[b][sp] = (short)bp; sp += 1;
        } else {
            const int rs = stck[b][sp - 1];
            const int ls = stck[b][sp - 2];
            const int l_lv = (ls < Tt) ? 0 : (int)lvl[b][ls - Tt];
            const int r_lv = (rs < Tt) ? 0 : (int)lvl[b][rs - Tt];
            const int le = 1 + (l_lv > r_lv ? l_lv : r_lv);
            lvl[b][nid] = (unsigned char)le;
            node_l[b * NNODE + nid] = (l_lv << 9) | ls;
            node_r[b * NNODE + nid] = (r_lv << 9) | rs;
            if (le > maxl) maxl = le;
            if (nid == 0) {
                if (!(ls < Tt && rs < Tt)) fast = 0;
                meta1 = (u32)ls | ((u32)rs << 9);
            } else {
                const int lhot = (ls == Tt + nid - 1);
                const int rhot = (rs == Tt + nid - 1);
                const int cold = lhot ? rs : ls;
                if (!((lhot ^ rhot) && cold < Tt)) fast = 0;
                fmG[(nid + 1) * GBATCH + bloc] =
                    (u32)cold | ((u32)(rhot ? 1 : 0) << 9)
                    | ((nid == NNODE - 1) ? (1u << 10) : 0u);
            }
            if (le != nid + 1) fast = 0;
            sp -= 2;
            stck[b][sp] = (short)(Tt + nid); sp += 1;
            nid += 1;
        }
    }
    if (nid != NNODE || sp != 1 || stck[b][0] != Tt + NNODE - 1) fast = 0;
    fmG[1 * GBATCH + bloc] = meta1;
    root_src[b] = (int)stck[b][0];
    for (int i = 0; i < nid; i++) atomicAdd(&counts[grp][lvl[b][i]], 1);
    atomicMax(&maxl_s[grp], maxl);
    atomicAnd(&fastsh[grp], fast);
    __syncthreads();
    if (b < NG) {
        int acc = 0;
        for (int l = 0; l < 256; l++) { offs_s[b][l] = acc; acc += counts[b][l]; }
        offs_s[b][256] = acc;
        max_lv[b] = maxl_s[b];
        fastflag[b] = fastsh[b];
    }
    __syncthreads();
    for (int i = b; i < NG * 256; i += Bb) counts[i >> 8][i & 255] = offs_s[i >> 8][i & 255];
    __syncthreads();
    for (int i = 0; i < nid; i++) {
        const int pos = atomicAdd(&counts[grp][lvl[b][i]], 1);
        items[grp * (GBATCH * NNODE) + pos] = (b << 16) | i;
    }
    for (int i = b; i < NG * 257; i += Bb) offs[i] = offs_s[i / 257][i % 257];
}

// ---------------------------------------------------------------------------
// Phase 3: 4 groups x 64 blocks; block (grp, mem) holds 40 W_r cols in LDS.
// FAST path (chain trees) — R11: back to the PROVEN R7 protocol (byte-slot
// barrier + sc1 publishes + CACHED hot gather from node_h; lines unique per
// node, written pre-barrier / read post-barrier) — the R10 mailbox's sc1
// polling congested the LLC (FETCH 413->493 MB, slower). Chain special-
// ization kept: fmeta metadata, hot c in REGISTERS (self-produced), h-only
// publish (1 ast32/lane), 2 syncthreads/level with parity-buffered Csf and
// wave-0 fused reduce+cell+publish; cold leaf A/c prefetched pre-barrier.
// GENERIC fallback = R7 path (proven), unchanged.
// ---------------------------------------------------------------------------
__global__ __launch_bounds__(512) void tree_kernel(
    const float* __restrict__ Wr, const float* __restrict__ br,
    const __hip_bfloat16* __restrict__ leaf_h, const float* __restrict__ leaf_c,
    __hip_bfloat16* __restrict__ node_h, float* __restrict__ node_c,
    const int* __restrict__ node_l, const int* __restrict__ node_r,
    const int* __restrict__ root_src, const int* __restrict__ offs,
    const int* __restrict__ items, const int* __restrict__ max_lv,
    float* __restrict__ out, int* __restrict__ slots,
    const u32* __restrict__ fmeta, u8* __restrict__ mb,
    const int* __restrict__ fastflag)
{
    __shared__ __align__(16) __bf16 Wt[48][1032];  // [local col][k], pad +8
    __shared__ __align__(16) char pool[49408];     // fast csf [2][8][16][CSTR] / generic structs
    __shared__ float brs[48];

    const int tid = threadIdx.x;
    const int blk = blockIdx.x;
    const int grp = blk & 3;
    const int mem = blk >> 2;  // 0..63
    const int j0 = mem * JPB;
    (void)mb;

    // Load W_r slice bf16 transposed: local col c -> (gate=c%5, jl=c/5).
    for (int idx = tid; idx < 48 * 1024; idx += 512) {
        const int c = idx >> 10;
        const int k = idx & 1023;
        float v = 0.f;
        if (c < NC) v = Wr[(long)k * N5H + (c % 5) * Hh + j0 + c / 5];
        Wt[c][k] = (__bf16)v;
    }
    if (tid < 48) {
        float v = 0.f;
        if (tid < NC) v = br[(tid % 5) * Hh + j0 + tid / 5];
        brs[tid] = v;
    }
    __syncthreads();

    const int ML = max_lv[grp];
    const int wave = tid >> 6;
    const int lane = tid & 63;
    const int quad = lane >> 4;
    const int l15 = lane & 15;
    const int kq = wave;           // K slice [kq*128, +128); kq<4 left child
    const bool rightW = kq >= 4;
    u8* slotG = (u8*)slots + grp * 256;
    u32* node_h32 = (u32*)node_h;

    if (fastflag[grp]) {
        // =================== FAST (chain) PATH ===================
        float* csf = (float*)pool;  // [2][8][16][CSTR]
        const int em = lane >> 2, ejj = (lane & 3) * 2;
        const u32* metaG = fmeta + grp * 256 * GBATCH;
        const long bL = (long)(grp * GBATCH + l15);  // batch for this lane's A rows
        const long bE = (long)(grp * GBATCH + em);   // batch for epilogue lane

        float bias[10];
        if (wave == 0) {
#pragma unroll
            for (int i = 0; i < 10; i++) bias[i] = brs[ejj * 5 + i];
        }
        float cv0 = 0.f, cv1 = 0.f;            // own c (hot source, registers)
        float ccold0 = 0.f, ccold1 = 0.f;      // cold (leaf) c for current lev
        float cnx0 = 0.f, cnx1 = 0.f;          // prefetched for lev+1
        float cl10 = 0.f, cl11 = 0.f, cr10 = 0.f, cr11 = 0.f;  // lev1 both-leaf c

        u32 meta_c = metaG[1 * GBATCH + l15];
        u32 meta_n = metaG[2 * GBATCH + l15];
        u32 metaE_c = 0, metaE_n = 0;
        if (wave == 0) {
            metaE_c = metaG[1 * GBATCH + em];
            metaE_n = metaG[2 * GBATCH + em];
            const int llf = metaE_c & 511, rlf = (metaE_c >> 9) & 511;
            const float* clp = leaf_c + (bE * Tt + llf) * Hh + j0 + ejj;
            const float* crp = leaf_c + (bE * Tt + rlf) * Hh + j0 + ejj;
            cl10 = clp[0]; cl11 = clp[1]; cr10 = crp[0]; cr11 = crp[1];
        }
        // lev1 A prefetch (both children leaves), cached
        v8bf a0, a1, a2, a3;
        {
            const int lf = rightW ? ((meta_c >> 9) & 511) : (meta_c & 511);
            const __hip_bfloat16* hp =
                leaf_h + (bL * Tt + lf) * Hh + (kq & 3) * 128 + quad * 8;
            a0 = *(const v8bf*)hp;        a1 = *(const v8bf*)(hp + 32);
            a2 = *(const v8bf*)(hp + 64); a3 = *(const v8bf*)(hp + 96);
        }

        for (int lev = 1; lev <= ML; lev++) {
            const int par = lev & 1;

            // ---- Barrier: wave 0 polls the group's 64-byte slot line ----
            if (lev > 1 && wave == 0) {
                const u32 need = (u32)(lev - 1);
                const u32* sl = (const u32*)slotG + (lane & 15);
                for (;;) {
                    const u32 v = ald32(sl);
                    const bool ok = ((v & 0xffu) >= need) & (((v >> 8) & 0xffu) >= need)
                                  & (((v >> 16) & 0xffu) >= need) & ((v >> 24) >= need);
                    if (__all(ok)) break;
                }
            }
            __syncthreads();  // sync 1: level lev-1 globally complete

            // ---- Hot gather (CACHED loads from node_h; line unique/node) ----
            const bool hot = (lev >= 2) && ((((meta_c >> 9) & 1)) == (rightW ? 1u : 0u));
            if (hot) {
                const __hip_bfloat16* hp =
                    node_h + (bL * NNODE + (lev - 2)) * Hh + (kq & 3) * 128 + quad * 8;
                a0 = *(const v8bf*)hp;        a1 = *(const v8bf*)(hp + 32);
                a2 = *(const v8bf*)(hp + 64); a3 = *(const v8bf*)(hp + 96);
            }
            // ---- MFMA into parity buffer ----
            {
                v8bf av[4] = {a0, a1, a2, a3};
#pragma unroll
                for (int nt = 0; nt < 3; nt++) {
                    v4f acc = {0.f, 0.f, 0.f, 0.f};
#pragma unroll
                    for (int t = 0; t < 4; t++) {
                        const v8bf wv = *(const v8bf*)&Wt[nt * 16 + l15][kq * 128 + t * 32 + quad * 8];
                        acc = __builtin_amdgcn_mfma_f32_16x16x32_bf16(av[t], wv, acc, 0, 0, 0);
                    }
#pragma unroll
                    for (int rg = 0; rg < 4; rg++)
                        csf[(((par * 8) + kq) * 16 + quad * 4 + rg) * CSTR + nt * 16 + l15] = acc[rg];
                }
            }
            // ---- Prefetch for lev+1 (cold leaf A / cold c / meta), cached ----
            u32 meta_nn = 0, metaE_nn = 0;
            if (lev < ML) {
                const int l2 = (lev + 2 <= ML) ? (lev + 2) : ML;
                meta_nn = metaG[l2 * GBATCH + l15];
                const bool nhot = (((meta_n >> 9) & 1)) == (rightW ? 1u : 0u);
                if (!nhot) {
                    const int lf = meta_n & 511;
                    const __hip_bfloat16* hp =
                        leaf_h + (bL * Tt + lf) * Hh + (kq & 3) * 128 + quad * 8;
                    a0 = *(const v8bf*)hp;        a1 = *(const v8bf*)(hp + 32);
                    a2 = *(const v8bf*)(hp + 64); a3 = *(const v8bf*)(hp + 96);
                }
                if (wave == 0) {
                    metaE_nn = metaG[l2 * GBATCH + em];
                    const int lfE = metaE_n & 511;
                    const float* cp = leaf_c + (bE * Tt + lfE) * Hh + j0 + ejj;
                    cnx0 = cp[0]; cnx1 = cp[1];
                }
            }
            __syncthreads();  // sync 2: csf[par] complete

            // ---- Wave-0 tail: fused reduce + cell + publish + arrive ----
            if (wave == 0) {
                float g10[10];
#pragma unroll
                for (int gi = 0; gi < 10; gi++) {
                    float s = bias[gi];
#pragma unroll
                    for (int w = 0; w < 8; w++)
                        s += csf[(((par * 8) + w) * 16 + em) * CSTR + ejj * 5 + gi];
                    g10[gi] = s;
                }
                float cl0, cl1, cr0, cr1;
                if (lev == 1) { cl0 = cl10; cl1 = cl11; cr0 = cr10; cr1 = cr11; }
                else if (((metaE_c >> 9) & 1) == 0) {  // left hot
                    cl0 = cv0; cl1 = cv1; cr0 = ccold0; cr1 = ccold1;
                } else {
                    cl0 = ccold0; cl1 = ccold1; cr0 = cv0; cr1 = cv1;
                }
                const float c0 = sigm(g10[0]) * tanhf(g10[3]) + sigm(g10[1]) * cl0 + sigm(g10[2]) * cr0;
                const float h0v = sigm(g10[4]) * tanhf(c0);
                const float c1 = sigm(g10[5]) * tanhf(g10[8]) + sigm(g10[6]) * cl1 + sigm(g10[7]) * cr1;
                const float h1v = sigm(g10[9]) * tanhf(c1);
                cv0 = c0; cv1 = c1;
                if (lev < ML) {
                    // publish h pair (sc1 -> LLC); node nid = lev-1
                    const __hip_bfloat16 hb0 = __float2bfloat16(h0v);
                    const __hip_bfloat16 hb1 = __float2bfloat16(h1v);
                    const u32 hp2 = (u32)(*(const unsigned short*)&hb0)
                                  | ((u32)(*(const unsigned short*)&hb1) << 16);
                    ast32(node_h32 + (bE * NNODE + (lev - 1)) * (Hh / 2) + (j0 + ejj) / 2, hp2);
                }
                if (metaE_c & (1u << 10)) {
                    out[bE * Hh + j0 + ejj] = h0v;
                    out[bE * Hh + j0 + ejj + 1] = h1v;
                }
                // rotate epilogue-side prefetch state
                metaE_c = metaE_n; metaE_n = metaE_nn;
                ccold0 = cnx0; ccold1 = cnx1;
                // drain wave-0 stores to LLC, then arrive
                __builtin_amdgcn_s_waitcnt(0);
                if (lev < ML && lane == 0)
                    __hip_atomic_store(slotG + mem, (u8)lev,
                                       __ATOMIC_RELAXED, __HIP_MEMORY_SCOPE_AGENT);
            }
            meta_c = meta_n; meta_n = meta_nn;
        }
        return;
    }

    // =================== GENERIC PATH (R7, proven) ===================
    float (*CsG)[16][52] = (float (*)[16][52])pool;              // [8][16][52]
    float (*CredG)[44] = (float (*)[44])(pool + 26624);          // [16][44]
    u64* hPlG = (u64*)(pool + 29440);
    u64* hPrG = (u64*)(pool + 29568);
    u64* cPlG = (u64*)(pool + 29696);
    u64* cPrG = (u64*)(pool + 29824);
    int* outmG = (int*)(pool + 29952);

    const int* offsG = offs + grp * 257;
    const int* itemsG = items + grp * (GBATCH * NNODE);

    auto prep = [&](int base, int M, int plv) {
        if (lane < 16) {
            const int m = lane;
            const int it = itemsG[base + (m < M ? m : 0)];
            const int b = it >> 16;
            const int nd = it & 0xffff;
            const int lraw = node_l[b * NNODE + nd];
            const int rraw = node_r[b * NNODE + nd];
            const int ls = lraw & 511, llv = lraw >> 9;
            const int rs = rraw & 511, rlv = rraw >> 9;
            hPlG[m] = (ls < Tt) ? (u64)(leaf_h + ((long)b * Tt + ls) * Hh)
                                : (u64)(node_h + ((long)b * NNODE + (ls - Tt)) * Hh);
            cPlG[m] = (ls < Tt) ? (u64)(leaf_c + ((long)b * Tt + ls) * Hh)
                                : (u64)(node_c + ((long)b * NNODE + (ls - Tt)) * Hh);
            hPrG[m] = (rs < Tt) ? (u64)(leaf_h + ((long)b * Tt + rs) * Hh)
                                : (u64)(node_h + ((long)b * NNODE + (rs - Tt)) * Hh);
            cPrG[m] = (rs < Tt) ? (u64)(leaf_c + ((long)b * Tt + rs) * Hh)
                                : (u64)(node_c + ((long)b * NNODE + (rs - Tt)) * Hh);
            int fl = it;
            if (llv > 0 && llv == plv - 1) fl |= (1 << 27);
            if (rlv > 0 && rlv == plv - 1) fl |= (1 << 28);
            if (Tt + nd == root_src[b]) fl |= (1 << 30);
            if (m >= M) fl |= (1 << 29);
            outmG[m] = fl;
        }
    };

    auto epilogue = [&](float clv0, float clv1, float crv0, float crv1) {
        const int m = lane >> 2;
        const int jl2 = (lane & 3) * 2;
        const int info = outmG[m];
        if (!(info & (1 << 29))) {
            const int b = (info >> 16) & 63;
            const int nd = info & 0xffff;
            float cv[2], hv[2];
            const float clv[2] = {clv0, clv1};
            const float crv[2] = {crv0, crv1};
#pragma unroll
            for (int jj = 0; jj < 2; jj++) {
                const int jc = (jl2 + jj) * 5;
                const float iv = CredG[m][jc + 0];
                const float fl = CredG[m][jc + 1];
                const float fr = CredG[m][jc + 2];
                const float gv = CredG[m][jc + 3];
                const float ov = CredG[m][jc + 4];
                cv[jj] = sigm(iv) * tanhf(gv) + sigm(fl) * clv[jj] + sigm(fr) * crv[jj];
                hv[jj] = sigm(ov) * tanhf(cv[jj]);
            }
            union { float f[2]; u64 u; } cp;
            cp.f[0] = cv[0]; cp.f[1] = cv[1];
            ast64((u64*)(node_c + ((long)b * NNODE + nd) * Hh + j0 + jl2), cp.u);
            const __hip_bfloat16 h0 = __float2bfloat16(hv[0]);
            const __hip_bfloat16 h1 = __float2bfloat16(hv[1]);
            const u32 hpack = (u32)(*(const unsigned short*)&h0)
                            | ((u32)(*(const unsigned short*)&h1) << 16);
            ast32(node_h32 + ((long)b * NNODE + nd) * (Hh / 2) + (j0 + jl2) / 2, hpack);
            if (info & (1 << 30)) {
                out[(long)b * Hh + j0 + jl2] = hv[0];
                out[(long)b * Hh + j0 + jl2 + 1] = hv[1];
            }
        }
    };

    auto do_mfma = [&](v8bf a0, v8bf a1, v8bf a2, v8bf a3) {
        v8bf a[4] = {a0, a1, a2, a3};
#pragma unroll
        for (int nt = 0; nt < 3; nt++) {
            v4f acc = {0.f, 0.f, 0.f, 0.f};
#pragma unroll
            for (int t = 0; t < 4; t++) {
                const v8bf wv = *(const v8bf*)&Wt[nt * 16 + l15][kq * 128 + t * 32 + quad * 8];
                acc = __builtin_amdgcn_mfma_f32_16x16x32_bf16(a[t], wv, acc, 0, 0, 0);
            }
#pragma unroll
            for (int rg = 0; rg < 4; rg++)
                CsG[kq][quad * 4 + rg][nt * 16 + l15] = acc[rg];
        }
    };

    auto reduce = [&]() {
        for (int t = tid; t < 16 * NC; t += 512) {
            const int m = t / NC, c = t - m * NC;
            float r = brs[c];
#pragma unroll
            for (int w = 0; w < 8; w++) r += CsG[w][m][c];
            CredG[m][c] = r;
        }
    };

    if (wave == 0 && ML >= 1) {
        const int s1 = offsG[1], e1 = offsG[2];
        prep(s1, (e1 - s1 < 16) ? (e1 - s1) : 16, 1);
    }
    __syncthreads();

    for (int lev = 1; lev <= ML; lev++) {
        const int s = offsG[lev], e = offsG[lev + 1];

        const int infoA = outmG[l15];
        const bool hot = (infoA >> (27 + (kq >> 2))) & 1;
        const __hip_bfloat16* hp =
            (const __hip_bfloat16*)((kq < 4) ? hPlG[l15] : hPrG[l15]);
        const int kb = (kq & 3) * 128 + quad * 8;
        v8bf a0, a1, a2, a3;
        if (!hot) {
            a0 = *(const v8bf*)(hp + kb);
            a1 = *(const v8bf*)(hp + kb + 32);
            a2 = *(const v8bf*)(hp + kb + 64);
            a3 = *(const v8bf*)(hp + kb + 96);
        }
        float clv0 = 0.f, clv1 = 0.f, crv0 = 0.f, crv1 = 0.f;
        bool hotL = false, hotR = false;
        if (wave == 0) {
            const int ie = outmG[lane >> 2];
            hotL = (ie >> 27) & 1;
            hotR = (ie >> 28) & 1;
            const int jo = j0 + (lane & 3) * 2;
            if (!hotL) {
                union { u64 u; float f[2]; } t;
                t.u = *(const u64*)((const float*)cPlG[lane >> 2] + jo);
                clv0 = t.f[0]; clv1 = t.f[1];
            }
            if (!hotR) {
                union { u64 u; float f[2]; } t;
                t.u = *(const u64*)((const float*)cPrG[lane >> 2] + jo);
                crv0 = t.f[0]; crv1 = t.f[1];
            }
        }

        if (lev > 1 && wave == 0) {
            const u32 need = (u32)(lev - 1);
            const u32* sl = (const u32*)slotG + (lane & 15);
            for (;;) {
                const u32 v = ald32(sl);
                const bool ok = ((v & 0xffu) >= need) & (((v >> 8) & 0xffu) >= need)
                              & (((v >> 16) & 0xffu) >= need) & ((v >> 24) >= need);
                if (__all(ok)) break;
            }
        }
        __syncthreads();

        if (hot) {
            a0 = *(const v8bf*)(hp + kb);
            a1 = *(const v8bf*)(hp + kb + 32);
            a2 = *(const v8bf*)(hp + kb + 64);
            a3 = *(const v8bf*)(hp + kb + 96);
        }
        if (wave == 0) {
            const int jo = j0 + (lane & 3) * 2;
            if (hotL) {
                union { u64 u; float f[2]; } t;
                t.u = *(const u64*)((const float*)cPlG[lane >> 2] + jo);
                clv0 = t.f[0]; clv1 = t.f[1];
            }
            if (hotR) {
                union { u64 u; float f[2]; } t;
                t.u = *(const u64*)((const float*)cPrG[lane >> 2] + jo);
                crv0 = t.f[0]; crv1 = t.f[1];
            }
        }
        do_mfma(a0, a1, a2, a3);
        __syncthreads();
        reduce();
        __syncthreads();
        if (wave == 0) epilogue(clv0, clv1, crv0, crv1);

        for (int base = s + 16; base < e; base += 16) {
            __syncthreads();
            if (wave == 0) prep(base, (e - base < 16) ? (e - base) : 16, lev);
            __syncthreads();
            const __hip_bfloat16* hp2 =
                (const __hip_bfloat16*)((kq < 4) ? hPlG[l15] : hPrG[l15]);
            float xl0 = 0.f, xl1 = 0.f, xr0 = 0.f, xr1 = 0.f;
            if (wave == 0) {
                const int jo = j0 + (lane & 3) * 2;
                union { u64 u; float f[2]; } t;
                t.u = *(const u64*)((const float*)cPlG[lane >> 2] + jo);
                xl0 = t.f[0]; xl1 = t.f[1];
                t.u = *(const u64*)((const float*)cPrG[lane >> 2] + jo);
                xr0 = t.f[0]; xr1 = t.f[1];
            }
            do_mfma(*(const v8bf*)(hp2 + kb), *(const v8bf*)(hp2 + kb + 32),
                    *(const v8bf*)(hp2 + kb + 64), *(const v8bf*)(hp2 + kb + 96));
            __syncthreads();
            reduce();
            __syncthreads();
            if (wave == 0) epilogue(xl0, xl1, xr0, xr1);
        }

        // arrival: drain wave-0 sc1 stores, then byte slot store + next prep
        if (wave == 0) {
            __builtin_amdgcn_s_waitcnt(0);
            if (lev < ML) {
                if (lane == 0)
                    __hip_atomic_store(slotG + mem, (u8)lev,
                                       __ATOMIC_RELAXED, __HIP_MEMORY_SCOPE_AGENT);
                const int ns = offsG[lev + 1], ne = offsG[lev + 2];
                prep(ns, (ne - ns < 16) ? (ne - ns) : 16, lev + 1);
            }
        }
        __syncthreads();
    }
}

// ---------------------------------------------------------------------------
extern "C" void kernel_launch(void* const* d_in, const int* in_sizes, int n_in,
                              void* d_out, int out_size, void* d_ws, size_t ws_size,
                              hipStream_t stream)
{
    const float* x   = (const float*)d_in[0];
    const int* trans = (const int*)d_in[1];
    const float* Wx  = (const float*)d_in[2];
    const float* bx  = (const float*)d_in[3];
    const float* Wg  = (const float*)d_in[4];
    const float* bg  = (const float*)d_in[5];
    const float* Wr  = (const float*)d_in[6];
    const float* br  = (const float*)d_in[7];
    float* out = (float*)d_out;

    char* p = (char*)d_ws;
    auto take = [&](size_t bytes) -> char* {
        char* r = p;
        p += (bytes + 255) & ~(size_t)255;
        return r;
    };
    __hip_bfloat16* leaf_h = (__hip_bfloat16*)take((size_t)Bb * Tt * Hh * 2);
    float* leaf_c          = (float*)take((size_t)Bb * Tt * Hh * 4);
    __hip_bfloat16* node_h = (__hip_bfloat16*)take((size_t)Bb * NNODE * Hh * 2);
    float* node_c          = (float*)take((size_t)Bb * NNODE * Hh * 4);
    int* node_l   = (int*)take((size_t)Bb * NNODE * 4);
    int* node_r   = (int*)take((size_t)Bb * NNODE * 4);
    int* root_src = (int*)take(Bb * 4);
    int* offs     = (int*)take((size_t)NG * 257 * 4);
    int* items    = (int*)take((size_t)NG * GBATCH * NNODE * 4);
    int* max_lv   = (int*)take(NG * 4);
    int* slots    = (int*)take(NG * 256);
    u32* fmeta    = (u32*)take((size_t)NG * 256 * GBATCH * 4);        // 64 KB
    u8* mbox      = (u8*)take((size_t)NG * 2 * GBATCH * 64 * MBREC);  // legacy, unused
    int* fastflag = (int*)take(NG * 4);

    hipLaunchKernelGGL(leaf_kernel, dim3(Hh / 256, (Bb * Tt) / LROWS), dim3(256), 0, stream,
                       x, Wx, bx, Wg, bg, leaf_h, leaf_c);
    hipLaunchKernelGGL(sched_kernel, dim3(1), dim3(64), 0, stream,
                       trans, node_l, node_r, root_src, offs, items, max_lv, slots,
                       fmeta, fastflag);

    void* args[] = { (void*)&Wr, (void*)&br, (void*)&leaf_h, (void*)&leaf_c,
                     (void*)&node_h, (void*)&node_c, (void*)&node_l, (void*)&node_r,
                     (void*)&root_src, (void*)&offs, (void*)&items, (void*)&max_lv,
                     (void*)&out, (void*)&slots, (void*)&fmeta, (void*)&mbox,
                     (void*)&fastflag };
    hipLaunchCooperativeKernel((const void*)tree_kernel, dim3(256), dim3(512),
                               args, 0, stream);
}